// Round 1
// baseline (687.223 us; speedup 1.0000x reference)
//
#include <hip/hip_runtime.h>

#define B 32
#define CL 1536
#define CG 192
#define T 256
#define MI 512
#define NPOS 8192   /* B*T */
#define EPS 1e-5f
#define TEMP 0.07f

// ---------------- reduction helpers (blockDim == 256) ----------------
__device__ __forceinline__ float wave_sum(float v) {
#pragma unroll
  for (int off = 32; off > 0; off >>= 1) v += __shfl_xor(v, off, 64);
  return v;
}
__device__ __forceinline__ float wave_max(float v) {
#pragma unroll
  for (int off = 32; off > 0; off >>= 1) v = fmaxf(v, __shfl_xor(v, off, 64));
  return v;
}
__device__ __forceinline__ float block_sum(float v, float* rb) {
  v = wave_sum(v);
  __syncthreads();
  if ((threadIdx.x & 63) == 0) rb[threadIdx.x >> 6] = v;
  __syncthreads();
  return rb[0] + rb[1] + rb[2] + rb[3];
}
__device__ __forceinline__ float block_max(float v, float* rb) {
  v = wave_max(v);
  __syncthreads();
  if ((threadIdx.x & 63) == 0) rb[threadIdx.x >> 6] = v;
  __syncthreads();
  return fmaxf(fmaxf(rb[0], rb[1]), fmaxf(rb[2], rb[3]));
}

// ---------------- 1: y1[b,o,t]=x·W1, ys[b,o,t]=x·Ws (dual GEMM, shares x) ----
__global__ __launch_bounds__(256) void k_gemm_x(
    const float* __restrict__ x, const float* __restrict__ W1,
    const float* __restrict__ Wsc, float* __restrict__ y1, float* __restrict__ ys) {
  __shared__ float xs[16][64];
  __shared__ float w1s[16][68];   // pad 64->68: bank-conflict-free writes, 16B-aligned rows
  __shared__ float wss[16][68];
  const int b = blockIdx.z;
  const int o0 = blockIdx.y * 64;
  const int t0 = blockIdx.x * 64;
  const int tid = threadIdx.x;
  const int tx = tid & 15, ty = tid >> 4;
  float a1[4][4] = {{0.f}}, a2[4][4] = {{0.f}};
  const float* xb = x + (size_t)b * CL * T;
  for (int c0 = 0; c0 < CL; c0 += 16) {
#pragma unroll
    for (int i = 0; i < 4; i++) {
      int e = tid + i * 256, cc = e >> 6, tt = e & 63;
      xs[cc][tt] = xb[(size_t)(c0 + cc) * T + t0 + tt];
    }
#pragma unroll
    for (int i = 0; i < 4; i++) {
      int e = tid + i * 256, oo = e >> 4, cc = e & 15;
      w1s[cc][oo] = W1[(size_t)(o0 + oo) * CL + c0 + cc];
      wss[cc][oo] = Wsc[(size_t)(o0 + oo) * CL + c0 + cc];
    }
    __syncthreads();
#pragma unroll
    for (int cc = 0; cc < 16; cc++) {
      float4 xv = *(const float4*)&xs[cc][tx * 4];
      float4 wv1 = *(const float4*)&w1s[cc][ty * 4];
      float4 wv2 = *(const float4*)&wss[cc][ty * 4];
      float xr[4] = {xv.x, xv.y, xv.z, xv.w};
      float w1r[4] = {wv1.x, wv1.y, wv1.z, wv1.w};
      float w2r[4] = {wv2.x, wv2.y, wv2.z, wv2.w};
#pragma unroll
      for (int i = 0; i < 4; i++)
#pragma unroll
        for (int j = 0; j < 4; j++) {
          a1[i][j] = fmaf(w1r[i], xr[j], a1[i][j]);
          a2[i][j] = fmaf(w2r[i], xr[j], a2[i][j]);
        }
    }
    __syncthreads();
  }
#pragma unroll
  for (int i = 0; i < 4; i++) {
    int o = o0 + ty * 4 + i;
    size_t base = ((size_t)b * MI + o) * T + t0 + tx * 4;
    float4 v1 = {a1[i][0], a1[i][1], a1[i][2], a1[i][3]};
    float4 v2 = {a2[i][0], a2[i][1], a2[i][2], a2[i][3]};
    *(float4*)&y1[base] = v1;
    *(float4*)&ys[base] = v2;
  }
}

// ---------------- 2: BatchNorm batch stats -> scale/shift per channel -------
__global__ __launch_bounds__(256) void k_bnstats(
    const float* __restrict__ y1, const float* __restrict__ g1,
    const float* __restrict__ b1, float* __restrict__ scale, float* __restrict__ shift) {
  __shared__ float rb[4];
  const int o = blockIdx.x;
  const int tid = threadIdx.x;
  float s = 0.f, s2 = 0.f;
  for (int b = 0; b < B; b++) {
    float v = y1[((size_t)b * MI + o) * T + tid];
    s += v;
    s2 = fmaf(v, v, s2);
  }
  s = block_sum(s, rb);
  s2 = block_sum(s2, rb);
  if (tid == 0) {
    float mu = s * (1.f / NPOS);
    float var = s2 * (1.f / NPOS) - mu * mu;
    float sc = g1[o] * rsqrtf(var + EPS);
    scale[o] = sc;
    shift[o] = b1[o] - mu * sc;
  }
}

// ---------------- 3: h = relu(bn(y1))·W2 + b2 + ys --------------------------
__global__ __launch_bounds__(256) void k_gemm2(
    const float* __restrict__ y1, const float* __restrict__ scale,
    const float* __restrict__ shift, const float* __restrict__ W2,
    const float* __restrict__ b2, const float* __restrict__ ys,
    float* __restrict__ h) {
  __shared__ float as[16][64];
  __shared__ float ws[16][68];
  const int b = blockIdx.z;
  const int p0 = blockIdx.y * 64;
  const int t0 = blockIdx.x * 64;
  const int tid = threadIdx.x;
  const int tx = tid & 15, ty = tid >> 4;
  float acc[4][4] = {{0.f}};
  const float* yb = y1 + (size_t)b * MI * T;
  for (int c0 = 0; c0 < MI; c0 += 16) {
#pragma unroll
    for (int i = 0; i < 4; i++) {
      int e = tid + i * 256, cc = e >> 6, tt = e & 63;
      int c = c0 + cc;
      float v = yb[(size_t)c * T + t0 + tt];
      as[cc][tt] = fmaxf(fmaf(v, scale[c], shift[c]), 0.f);
    }
#pragma unroll
    for (int i = 0; i < 4; i++) {
      int e = tid + i * 256, pp = e >> 4, cc = e & 15;
      ws[cc][pp] = W2[(size_t)(p0 + pp) * MI + c0 + cc];
    }
    __syncthreads();
#pragma unroll
    for (int cc = 0; cc < 16; cc++) {
      float4 av = *(const float4*)&as[cc][tx * 4];
      float4 wv = *(const float4*)&ws[cc][ty * 4];
      float ar[4] = {av.x, av.y, av.z, av.w};
      float wr[4] = {wv.x, wv.y, wv.z, wv.w};
#pragma unroll
      for (int i = 0; i < 4; i++)
#pragma unroll
        for (int j = 0; j < 4; j++) acc[i][j] = fmaf(wr[i], ar[j], acc[i][j]);
    }
    __syncthreads();
  }
#pragma unroll
  for (int i = 0; i < 4; i++) {
    int p = p0 + ty * 4 + i;
    float bias = b2[p];
    size_t base = ((size_t)b * MI + p) * T + t0 + tx * 4;
    float4 yv = *(const float4*)&ys[base];
    float4 o = {acc[i][0] + bias + yv.x, acc[i][1] + bias + yv.y,
                acc[i][2] + bias + yv.z, acc[i][3] + bias + yv.w};
    *(float4*)&h[base] = o;
  }
}

// ---------------- 4: LayerNorm over channels (in place) + 1/||L|| -----------
__global__ __launch_bounds__(256) void k_layernorm(
    float* __restrict__ h, const float* __restrict__ lng,
    const float* __restrict__ lnb, float* __restrict__ inv_norm) {
  const int b = blockIdx.y;
  const int t0 = blockIdx.x * 32;
  const int tid = threadIdx.x;
  const int tx = tid & 31, py = tid >> 5;  // 8 p-groups x 32 t
  const int t = t0 + tx;
  __shared__ float red[8][32];
  __shared__ float red2[8][32];
  __shared__ float mu_s[32], rstd_s[32];
  size_t base = (size_t)b * MI * T + t;
  float s = 0.f, s2 = 0.f;
  for (int p = py; p < MI; p += 8) {
    float v = h[base + (size_t)p * T];
    s += v;
    s2 = fmaf(v, v, s2);
  }
  red[py][tx] = s;
  red2[py][tx] = s2;
  __syncthreads();
  if (py == 0) {
    float ts = 0.f, ts2 = 0.f;
#pragma unroll
    for (int k = 0; k < 8; k++) { ts += red[k][tx]; ts2 += red2[k][tx]; }
    float mu = ts * (1.f / MI);
    float var = ts2 * (1.f / MI) - mu * mu;
    mu_s[tx] = mu;
    rstd_s[tx] = rsqrtf(var + EPS);
  }
  __syncthreads();
  float mu = mu_s[tx], rstd = rstd_s[tx];
  float n2 = 0.f;
  for (int p = py; p < MI; p += 8) {
    float v = h[base + (size_t)p * T];
    float Lv = fmaf((v - mu) * rstd, lng[p], lnb[p]);
    h[base + (size_t)p * T] = Lv;
    n2 = fmaf(Lv, Lv, n2);
  }
  __syncthreads();
  red[py][tx] = n2;
  __syncthreads();
  if (py == 0) {
    float tn = 0.f;
#pragma unroll
    for (int k = 0; k < 8; k++) tn += red[k][tx];
    inv_norm[b * T + t] = rsqrtf(tn);
  }
}

// ---------------- 5a-5d: global net (tiny, B=32, T=1) -----------------------
__global__ __launch_bounds__(256) void k_gnet1(
    const float* __restrict__ gx, const float* __restrict__ gW1, float* __restrict__ y1g) {
  int idx = blockIdx.x * 256 + threadIdx.x;  // 512*32 threads
  int b = idx & 31, o = idx >> 5;
  float s = 0.f;
  for (int c = 0; c < CG; c++) s = fmaf(gx[b * CG + c], gW1[o * CG + c], s);
  y1g[o * 32 + b] = s;
}

__global__ __launch_bounds__(256) void k_gbn(
    const float* __restrict__ y1g, const float* __restrict__ gg1,
    const float* __restrict__ gb1, float* __restrict__ gscale, float* __restrict__ gshift) {
  int o = blockIdx.x * 256 + threadIdx.x;  // 512 threads
  float s = 0.f, s2 = 0.f;
  for (int b = 0; b < 32; b++) {
    float v = y1g[o * 32 + b];
    s += v;
    s2 = fmaf(v, v, s2);
  }
  float mu = s * (1.f / 32.f);
  float var = s2 * (1.f / 32.f) - mu * mu;
  float sc = gg1[o] * rsqrtf(var + EPS);
  gscale[o] = sc;
  gshift[o] = gb1[o] - mu * sc;
}

__global__ __launch_bounds__(256) void k_gnet2(
    const float* __restrict__ y1g, const float* __restrict__ gscale,
    const float* __restrict__ gshift, const float* __restrict__ gW2,
    const float* __restrict__ gb2, const float* __restrict__ gx,
    const float* __restrict__ gWsc, float* __restrict__ hg) {
  int idx = blockIdx.x * 256 + threadIdx.x;
  int b = idx & 31, p = idx >> 5;
  float s = gb2[p];
  for (int o = 0; o < MI; o++) {
    float v = fmaxf(fmaf(y1g[o * 32 + b], gscale[o], gshift[o]), 0.f);
    s = fmaf(v, gW2[(size_t)p * MI + o], s);
  }
  for (int c = 0; c < CG; c++) s = fmaf(gx[b * CG + c], gWsc[p * CG + c], s);
  hg[p * 32 + b] = s;
}

__global__ __launch_bounds__(256) void k_gln(
    const float* __restrict__ hg, const float* __restrict__ glng,
    const float* __restrict__ glnb, float* __restrict__ gnorm) {
  __shared__ float rb[4];
  int b = blockIdx.x;
  int tid = threadIdx.x;
  float v0 = hg[tid * 32 + b];
  float v1 = hg[(tid + 256) * 32 + b];
  float s = block_sum(v0 + v1, rb);
  float s2 = block_sum(fmaf(v0, v0, v1 * v1), rb);
  float mu = s * (1.f / MI);
  float var = s2 * (1.f / MI) - mu * mu;
  float rstd = rsqrtf(var + EPS);
  float L0 = fmaf((v0 - mu) * rstd, glng[tid], glnb[tid]);
  float L1 = fmaf((v1 - mu) * rstd, glng[tid + 256], glnb[tid + 256]);
  float n2 = block_sum(fmaf(L0, L0, L1 * L1), rb);
  float inv = rsqrtf(n2);
  gnorm[b * MI + tid] = L0 * inv;
  gnorm[b * MI + tid + 256] = L1 * inv;
}

// ---------------- 6: U[n, m*T+t] = <g_n, L[m,:,t]> / ||L[m,:,t]|| -----------
__global__ __launch_bounds__(256) void k_u(
    const float* __restrict__ L, const float* __restrict__ inv_norm,
    const float* __restrict__ gnorm, float* __restrict__ U) {
  __shared__ float Ld[16][64];
  __shared__ float gs[16][32];
  const int m = blockIdx.y, t0 = blockIdx.x * 64;
  const int tid = threadIdx.x;
  const int tx = tid & 63, ty = tid >> 6;  // ty in 0..3 -> 8 n each
  float acc[8] = {};
  for (int d0 = 0; d0 < MI; d0 += 16) {
#pragma unroll
    for (int i = 0; i < 4; i++) {
      int e = tid + i * 256, dd = e >> 6, tt = e & 63;
      Ld[dd][tt] = L[((size_t)m * MI + d0 + dd) * T + t0 + tt];
    }
#pragma unroll
    for (int i = 0; i < 2; i++) {
      int e = tid + i * 256, dd = e >> 5, nn = e & 31;
      gs[dd][nn] = gnorm[nn * MI + d0 + dd];
    }
    __syncthreads();
#pragma unroll
    for (int dd = 0; dd < 16; dd++) {
      float lv = Ld[dd][tx];
#pragma unroll
      for (int i = 0; i < 8; i++) acc[i] = fmaf(gs[dd][ty * 8 + i], lv, acc[i]);
    }
    __syncthreads();
  }
  float inv = inv_norm[m * T + t0 + tx];
#pragma unroll
  for (int i = 0; i < 8; i++) {
    int n = ty * 8 + i;
    U[(size_t)n * NPOS + m * T + t0 + tx] = acc[i] * inv;
  }
}

// ---------------- 7: per-row masked max & sumexp ----------------------------
__global__ __launch_bounds__(256) void k_rowstats(
    const float* __restrict__ U, float* __restrict__ row_max, float* __restrict__ row_se) {
  __shared__ float sm[NPOS];  // 32 KB
  __shared__ float rb[4];
  const int n = blockIdx.x;
  const int tid = threadIdx.x;
  const float* row = U + (size_t)n * NPOS;
  float mx = -1e30f;
  for (int i = tid; i < NPOS; i += 256) {
    int m = i >> 8;
    float v = (m == n) ? -1e30f : row[i];  // exp underflows to exactly 0, same as ref's -1e9
    sm[i] = v;
    mx = fmaxf(mx, v);
  }
  mx = block_max(mx, rb);
  float s = 0.f;
  for (int i = tid; i < NPOS; i += 256) s += expf(sm[i] - mx);
  s = block_sum(s, rb);
  if (tid == 0) {
    row_max[n] = mx;
    row_se[n] = s;
  }
}

// ---------------- 8: loss = mean(lse - u_p) ---------------------------------
__global__ __launch_bounds__(256) void k_loss(
    const float* __restrict__ U, const float* __restrict__ row_max,
    const float* __restrict__ row_se, float* __restrict__ out) {
  __shared__ float rb[4];
  const int tid = threadIdx.x;
  float s = 0.f;
  for (int i = tid; i < NPOS; i += 256) {
    int n = i >> 8, t = i & 255;
    float up = U[(size_t)n * NPOS + n * T + t] * (1.f / TEMP);
    float rm = row_max[n], rs = row_se[n];
    float mx = fmaxf(up, rm);
    float lse = mx + logf(expf(up - mx) + rs * expf(rm - mx));
    s += lse - up;
  }
  s = block_sum(s, rb);
  if (tid == 0) out[0] = s * (1.f / NPOS);
}

extern "C" void kernel_launch(void* const* d_in, const int* in_sizes, int n_in,
                              void* d_out, int out_size, void* d_ws, size_t ws_size,
                              hipStream_t stream) {
  (void)in_sizes; (void)n_in; (void)out_size; (void)ws_size;
  const float* x    = (const float*)d_in[0];
  const float* gx   = (const float*)d_in[1];
  const float* lW1  = (const float*)d_in[2];
  const float* lg1  = (const float*)d_in[3];
  const float* lb1  = (const float*)d_in[4];
  const float* lW2  = (const float*)d_in[5];
  const float* lb2  = (const float*)d_in[6];
  const float* lWs  = (const float*)d_in[7];
  const float* llng = (const float*)d_in[8];
  const float* llnb = (const float*)d_in[9];
  const float* gW1  = (const float*)d_in[10];
  const float* gg1  = (const float*)d_in[11];
  const float* gb1  = (const float*)d_in[12];
  const float* gW2  = (const float*)d_in[13];
  const float* gb2  = (const float*)d_in[14];
  const float* gWs  = (const float*)d_in[15];
  const float* glng = (const float*)d_in[16];
  const float* glnb = (const float*)d_in[17];

  // workspace carve-up (floats); total ~51.5 MB
  float* wsp = (float*)d_ws;
  float* y1       = wsp; wsp += (size_t)B * MI * T;   // 16 MB
  float* ysb      = wsp; wsp += (size_t)B * MI * T;   // 16 MB
  float* hb       = wsp; wsp += (size_t)B * MI * T;   // 16 MB (h, then L in place)
  float* scl      = wsp; wsp += MI;
  float* shf      = wsp; wsp += MI;
  float* inv_norm = wsp; wsp += NPOS;
  float* y1g      = wsp; wsp += MI * 32;
  float* gscale   = wsp; wsp += MI;
  float* gshift   = wsp; wsp += MI;
  float* hg       = wsp; wsp += MI * 32;
  float* gnorm    = wsp; wsp += 32 * MI;
  float* U        = wsp; wsp += (size_t)32 * NPOS;    // 1 MB
  float* rmax     = wsp; wsp += 32;
  float* rse      = wsp; wsp += 32;

  k_gemm_x<<<dim3(4, 8, 32), 256, 0, stream>>>(x, lW1, lWs, y1, ysb);
  k_bnstats<<<dim3(512), 256, 0, stream>>>(y1, lg1, lb1, scl, shf);
  k_gemm2<<<dim3(4, 8, 32), 256, 0, stream>>>(y1, scl, shf, lW2, lb2, ysb, hb);
  k_layernorm<<<dim3(8, 32), 256, 0, stream>>>(hb, llng, llnb, inv_norm);
  k_gnet1<<<dim3(64), 256, 0, stream>>>(gx, gW1, y1g);
  k_gbn<<<dim3(2), 256, 0, stream>>>(y1g, gg1, gb1, gscale, gshift);
  k_gnet2<<<dim3(64), 256, 0, stream>>>(y1g, gscale, gshift, gW2, gb2, gx, gWs, hg);
  k_gln<<<dim3(32), 256, 0, stream>>>(hg, glng, glnb, gnorm);
  k_u<<<dim3(4, 32), 256, 0, stream>>>(hb, inv_norm, gnorm, U);
  k_rowstats<<<dim3(32), 256, 0, stream>>>(U, rmax, rse);
  k_loss<<<dim3(1), 256, 0, stream>>>(U, rmax, rse, (float*)d_out);
}

// Round 2
// 298.031 us; speedup vs baseline: 2.3059x; 2.3059x over previous
//
#include <hip/hip_runtime.h>

#define B 32
#define CL 1536
#define CG 192
#define T 256
#define MI 512
#define NPOS 8192   /* B*T */
#define EPS 1e-5f
#define TEMP 0.07f

typedef __attribute__((ext_vector_type(8))) __bf16 bf16x8;
typedef __attribute__((ext_vector_type(4))) float f32x4;

__device__ __forceinline__ unsigned short f2bf(float f) {
  union { float f; unsigned u; } v; v.f = f;
  unsigned r = v.u + 0x7FFFu + ((v.u >> 16) & 1u);
  return (unsigned short)(r >> 16);
}
__device__ __forceinline__ float bf2f(unsigned short h) {
  union { unsigned u; float f; } v; v.u = ((unsigned)h) << 16;
  return v.f;
}

// ---------------- reduction helpers (blockDim == 256) ----------------
__device__ __forceinline__ float wave_sum(float v) {
#pragma unroll
  for (int off = 32; off > 0; off >>= 1) v += __shfl_xor(v, off, 64);
  return v;
}
__device__ __forceinline__ float wave_max(float v) {
#pragma unroll
  for (int off = 32; off > 0; off >>= 1) v = fmaxf(v, __shfl_xor(v, off, 64));
  return v;
}
__device__ __forceinline__ float block_sum(float v, float* rb) {
  v = wave_sum(v);
  __syncthreads();
  if ((threadIdx.x & 63) == 0) rb[threadIdx.x >> 6] = v;
  __syncthreads();
  return rb[0] + rb[1] + rb[2] + rb[3];
}
__device__ __forceinline__ float block_max(float v, float* rb) {
  v = wave_max(v);
  __syncthreads();
  if ((threadIdx.x & 63) == 0) rb[threadIdx.x >> 6] = v;
  __syncthreads();
  return fmaxf(fmaxf(rb[0], rb[1]), fmaxf(rb[2], rb[3]));
}

// ---------------- 0a: cast W1||Ws -> Wcat[1024][1536] bf16, W2 -> W2b -------
__global__ __launch_bounds__(256) void k_castw(
    const float* __restrict__ lW1, const float* __restrict__ lWs,
    const float* __restrict__ lW2, unsigned short* __restrict__ Wc,
    unsigned short* __restrict__ W2b) {
  int idx = (blockIdx.x * 256 + threadIdx.x) * 4;
  const float* src; unsigned short* dst;
  if (idx < 786432) { src = lW1 + idx; dst = Wc + idx; }
  else if (idx < 1572864) { src = lWs + (idx - 786432); dst = Wc + idx; }
  else { src = lW2 + (idx - 1572864); dst = W2b + (idx - 1572864); }
  float4 v = *(const float4*)src;
  ushort4 o = {f2bf(v.x), f2bf(v.y), f2bf(v.z), f2bf(v.w)};
  *(ushort4*)dst = o;
}

// ---------------- 0b: x [b][c][t] fp32 -> xT [b*T+t][c] bf16 ----------------
__global__ __launch_bounds__(256) void k_transpose(
    const float* __restrict__ x, unsigned short* __restrict__ xT) {
  __shared__ float xs[64][65];
  const int b = blockIdx.z, c0 = blockIdx.y * 64, t0 = blockIdx.x * 64;
  const int tid = threadIdx.x;
  const float* xb = x + ((size_t)b * CL + c0) * T + t0;
#pragma unroll
  for (int i = 0; i < 16; i++) {
    int idx = tid + i * 256, c = idx >> 6, t = idx & 63;
    xs[c][t] = xb[(size_t)c * T + t];
  }
  __syncthreads();
  unsigned short* ob = xT + ((size_t)b * T + t0) * CL + c0;
#pragma unroll
  for (int i = 0; i < 8; i++) {
    int idx = tid + i * 256, t = idx >> 5, k = (idx & 31) * 2;
    ushort2 v = {f2bf(xs[k][t]), f2bf(xs[k + 1][t])};
    *(ushort2*)&ob[(size_t)t * CL + k] = v;
  }
}

// ---------------- 1: dual GEMM via MFMA: [8192][1536] x [1024][1536]^T ------
// A=xT rows (M), B=Wcat rows (N: 0..511 -> y1, 512..1023 -> ys)
__global__ __launch_bounds__(256) void k_gemm1(
    const unsigned short* __restrict__ xT, const unsigned short* __restrict__ Wc,
    unsigned short* __restrict__ y1u, unsigned short* __restrict__ ysb) {
  __shared__ __align__(16) unsigned short As[128][32];
  __shared__ __align__(16) unsigned short Bs[128][32];
  const int tid = threadIdx.x;
  const int w = tid >> 6, lane = tid & 63;
  const int m0 = blockIdx.x * 128, o0 = blockIdx.y * 128;
  const int sr = lane >> 2;            // staging: row within 16-row chunk
  const int sc = (lane & 3) * 8;       // staging: bf16 col offset (16B chunks)
  const int wm = w & 1, wn = w >> 1;   // wave -> 64x64 subtile (2x2)
  const int lm = lane & 15, q = lane >> 4;
  f32x4 acc[4][4];
#pragma unroll
  for (int i = 0; i < 4; i++)
#pragma unroll
    for (int j = 0; j < 4; j++) acc[i][j] = f32x4{0.f, 0.f, 0.f, 0.f};

  const unsigned short* pa0 = xT + (size_t)(m0 + w * 32 + sr) * CL + sc;
  const unsigned short* pa1 = pa0 + (size_t)16 * CL;
  const unsigned short* pb0 = Wc + (size_t)(o0 + w * 32 + sr) * CL + sc;
  const unsigned short* pb1 = pb0 + (size_t)16 * CL;
  for (int c0 = 0; c0 < CL; c0 += 32) {
    __builtin_amdgcn_global_load_lds(
        (const __attribute__((address_space(1))) void*)(pa0 + c0),
        (__attribute__((address_space(3))) void*)&As[w * 32][0], 16, 0, 0);
    __builtin_amdgcn_global_load_lds(
        (const __attribute__((address_space(1))) void*)(pa1 + c0),
        (__attribute__((address_space(3))) void*)&As[w * 32 + 16][0], 16, 0, 0);
    __builtin_amdgcn_global_load_lds(
        (const __attribute__((address_space(1))) void*)(pb0 + c0),
        (__attribute__((address_space(3))) void*)&Bs[w * 32][0], 16, 0, 0);
    __builtin_amdgcn_global_load_lds(
        (const __attribute__((address_space(1))) void*)(pb1 + c0),
        (__attribute__((address_space(3))) void*)&Bs[w * 32 + 16][0], 16, 0, 0);
    __syncthreads();
    bf16x8 af[4], bfr[4];
#pragma unroll
    for (int mi = 0; mi < 4; mi++)
      af[mi] = *(const bf16x8*)&As[wm * 64 + mi * 16 + lm][q * 8];
#pragma unroll
    for (int ni = 0; ni < 4; ni++)
      bfr[ni] = *(const bf16x8*)&Bs[wn * 64 + ni * 16 + lm][q * 8];
#pragma unroll
    for (int mi = 0; mi < 4; mi++)
#pragma unroll
      for (int ni = 0; ni < 4; ni++)
        acc[mi][ni] = __builtin_amdgcn_mfma_f32_16x16x32_bf16(
            af[mi], bfr[ni], acc[mi][ni], 0, 0, 0);
    __syncthreads();
  }
  const int row0 = m0 + wm * 64 + q * 4;
  if (o0 < 512) {
#pragma unroll
    for (int mi = 0; mi < 4; mi++)
#pragma unroll
      for (int ni = 0; ni < 4; ni++) {
        int oc = o0 + wn * 64 + ni * 16 + lm;
#pragma unroll
        for (int r = 0; r < 4; r++)
          y1u[(size_t)(row0 + mi * 16 + r) * 512 + oc] = f2bf(acc[mi][ni][r]);
      }
  } else {
#pragma unroll
    for (int mi = 0; mi < 4; mi++)
#pragma unroll
      for (int ni = 0; ni < 4; ni++) {
        int oc = o0 - 512 + wn * 64 + ni * 16 + lm;
#pragma unroll
        for (int r = 0; r < 4; r++)
          ysb[(size_t)(row0 + mi * 16 + r) * 512 + oc] = f2bf(acc[mi][ni][r]);
      }
  }
}

// ---------------- 2a/2b: BN batch stats (two-phase) -------------------------
__global__ __launch_bounds__(256) void k_bnstat1(
    const unsigned short* __restrict__ y1u, float* __restrict__ ps, float* __restrict__ ps2) {
  const int j = blockIdx.x, tid = threadIdx.x;
  float s0 = 0.f, s20 = 0.f, s1 = 0.f, s21 = 0.f;
  const unsigned short* base = y1u + (size_t)j * 64 * 512;
  for (int r = 0; r < 64; r++) {
    float a = bf2f(base[r * 512 + tid]);
    float b = bf2f(base[r * 512 + tid + 256]);
    s0 += a; s20 = fmaf(a, a, s20);
    s1 += b; s21 = fmaf(b, b, s21);
  }
  ps[j * 512 + tid] = s0; ps[j * 512 + tid + 256] = s1;
  ps2[j * 512 + tid] = s20; ps2[j * 512 + tid + 256] = s21;
}

__global__ __launch_bounds__(256) void k_bnstat2(
    const float* __restrict__ ps, const float* __restrict__ ps2,
    const float* __restrict__ g1, const float* __restrict__ b1,
    float* __restrict__ scl, float* __restrict__ shf) {
  int o = blockIdx.x * 256 + threadIdx.x;
  float s = 0.f, s2 = 0.f;
  for (int j = 0; j < 128; j++) { s += ps[j * 512 + o]; s2 += ps2[j * 512 + o]; }
  float mu = s * (1.f / NPOS);
  float var = s2 * (1.f / NPOS) - mu * mu;
  float sc = g1[o] * rsqrtf(var + EPS);
  scl[o] = sc;
  shf[o] = b1[o] - mu * sc;
}

// ---------------- 2c: v = bf16(relu(bn(y1))) --------------------------------
__global__ __launch_bounds__(256) void k_bnapply(
    const unsigned short* __restrict__ y1u, const float* __restrict__ scl,
    const float* __restrict__ shf, unsigned short* __restrict__ v) {
  int idx = (blockIdx.x * 256 + threadIdx.x) * 4;
  int o = idx & 511;
  ushort4 in = *(const ushort4*)&y1u[idx];
  ushort4 out;
  out.x = f2bf(fmaxf(fmaf(bf2f(in.x), scl[o], shf[o]), 0.f));
  out.y = f2bf(fmaxf(fmaf(bf2f(in.y), scl[o + 1], shf[o + 1]), 0.f));
  out.z = f2bf(fmaxf(fmaf(bf2f(in.z), scl[o + 2], shf[o + 2]), 0.f));
  out.w = f2bf(fmaxf(fmaf(bf2f(in.w), scl[o + 3], shf[o + 3]), 0.f));
  *(ushort4*)&v[idx] = out;
}

// ---------------- 3: h = v·W2^T + b2 + ys (MFMA) ----------------------------
__global__ __launch_bounds__(256) void k_gemm2(
    const unsigned short* __restrict__ vv, const unsigned short* __restrict__ W2b,
    const float* __restrict__ b2, const unsigned short* __restrict__ ysb,
    float* __restrict__ h) {
  __shared__ __align__(16) unsigned short As[128][32];
  __shared__ __align__(16) unsigned short Bs[128][32];
  const int tid = threadIdx.x;
  const int w = tid >> 6, lane = tid & 63;
  const int m0 = blockIdx.x * 128, p0 = blockIdx.y * 128;
  const int sr = lane >> 2, sc = (lane & 3) * 8;
  const int wm = w & 1, wn = w >> 1;
  const int lm = lane & 15, q = lane >> 4;
  f32x4 acc[4][4];
#pragma unroll
  for (int i = 0; i < 4; i++)
#pragma unroll
    for (int j = 0; j < 4; j++) acc[i][j] = f32x4{0.f, 0.f, 0.f, 0.f};

  const unsigned short* pa0 = vv + (size_t)(m0 + w * 32 + sr) * 512 + sc;
  const unsigned short* pa1 = pa0 + (size_t)16 * 512;
  const unsigned short* pb0 = W2b + (size_t)(p0 + w * 32 + sr) * 512 + sc;
  const unsigned short* pb1 = pb0 + (size_t)16 * 512;
  for (int c0 = 0; c0 < 512; c0 += 32) {
    __builtin_amdgcn_global_load_lds(
        (const __attribute__((address_space(1))) void*)(pa0 + c0),
        (__attribute__((address_space(3))) void*)&As[w * 32][0], 16, 0, 0);
    __builtin_amdgcn_global_load_lds(
        (const __attribute__((address_space(1))) void*)(pa1 + c0),
        (__attribute__((address_space(3))) void*)&As[w * 32 + 16][0], 16, 0, 0);
    __builtin_amdgcn_global_load_lds(
        (const __attribute__((address_space(1))) void*)(pb0 + c0),
        (__attribute__((address_space(3))) void*)&Bs[w * 32][0], 16, 0, 0);
    __builtin_amdgcn_global_load_lds(
        (const __attribute__((address_space(1))) void*)(pb1 + c0),
        (__attribute__((address_space(3))) void*)&Bs[w * 32 + 16][0], 16, 0, 0);
    __syncthreads();
    bf16x8 af[4], bfr[4];
#pragma unroll
    for (int mi = 0; mi < 4; mi++)
      af[mi] = *(const bf16x8*)&As[wm * 64 + mi * 16 + lm][q * 8];
#pragma unroll
    for (int ni = 0; ni < 4; ni++)
      bfr[ni] = *(const bf16x8*)&Bs[wn * 64 + ni * 16 + lm][q * 8];
#pragma unroll
    for (int mi = 0; mi < 4; mi++)
#pragma unroll
      for (int ni = 0; ni < 4; ni++)
        acc[mi][ni] = __builtin_amdgcn_mfma_f32_16x16x32_bf16(
            af[mi], bfr[ni], acc[mi][ni], 0, 0, 0);
    __syncthreads();
  }
  const int row0 = m0 + wm * 64 + q * 4;
#pragma unroll
  for (int ni = 0; ni < 4; ni++) {
    int p = p0 + wn * 64 + ni * 16 + lm;
    float bias = b2[p];
#pragma unroll
    for (int mi = 0; mi < 4; mi++)
#pragma unroll
      for (int r = 0; r < 4; r++) {
        size_t off = (size_t)(row0 + mi * 16 + r) * 512 + p;
        h[off] = acc[mi][ni][r] + bias + bf2f(ysb[off]);
      }
  }
}

// ---------------- 4: LayerNorm per row (contig 512) + 1/||L|| ---------------
__global__ __launch_bounds__(256) void k_ln(
    float* __restrict__ h, const float* __restrict__ lng,
    const float* __restrict__ lnb, float* __restrict__ inv_norm) {
  __shared__ float rb[4];
  const int r = blockIdx.x, tid = threadIdx.x;
  float* row = h + (size_t)r * 512;
  float v0 = row[tid], v1 = row[tid + 256];
  float s = block_sum(v0 + v1, rb);
  float s2 = block_sum(fmaf(v0, v0, v1 * v1), rb);
  float mu = s * (1.f / MI);
  float var = s2 * (1.f / MI) - mu * mu;
  float rstd = rsqrtf(var + EPS);
  float L0 = fmaf((v0 - mu) * rstd, lng[tid], lnb[tid]);
  float L1 = fmaf((v1 - mu) * rstd, lng[tid + 256], lnb[tid + 256]);
  float n2 = block_sum(fmaf(L0, L0, L1 * L1), rb);
  row[tid] = L0;
  row[tid + 256] = L1;
  if (tid == 0) inv_norm[r] = rsqrtf(n2);
}

// ---------------- 5a-5d: global net (tiny, fp32) ----------------------------
__global__ __launch_bounds__(256) void k_gnet1(
    const float* __restrict__ gx, const float* __restrict__ gW1, float* __restrict__ y1g) {
  int idx = blockIdx.x * 256 + threadIdx.x;
  int b = idx & 31, o = idx >> 5;
  float s = 0.f;
  for (int c = 0; c < CG; c++) s = fmaf(gx[b * CG + c], gW1[o * CG + c], s);
  y1g[o * 32 + b] = s;
}

__global__ __launch_bounds__(256) void k_gbn(
    const float* __restrict__ y1g, const float* __restrict__ gg1,
    const float* __restrict__ gb1, float* __restrict__ gscale, float* __restrict__ gshift) {
  int o = blockIdx.x * 256 + threadIdx.x;
  float s = 0.f, s2 = 0.f;
  for (int b = 0; b < 32; b++) {
    float v = y1g[o * 32 + b];
    s += v;
    s2 = fmaf(v, v, s2);
  }
  float mu = s * (1.f / 32.f);
  float var = s2 * (1.f / 32.f) - mu * mu;
  float sc = gg1[o] * rsqrtf(var + EPS);
  gscale[o] = sc;
  gshift[o] = gb1[o] - mu * sc;
}

__global__ __launch_bounds__(256) void k_gnet2(
    const float* __restrict__ y1g, const float* __restrict__ gscale,
    const float* __restrict__ gshift, const float* __restrict__ gW2,
    const float* __restrict__ gb2, const float* __restrict__ gx,
    const float* __restrict__ gWsc, float* __restrict__ hg) {
  int idx = blockIdx.x * 256 + threadIdx.x;
  int b = idx & 31, p = idx >> 5;
  float s = gb2[p];
  for (int o = 0; o < MI; o++) {
    float v = fmaxf(fmaf(y1g[o * 32 + b], gscale[o], gshift[o]), 0.f);
    s = fmaf(v, gW2[(size_t)p * MI + o], s);
  }
  for (int c = 0; c < CG; c++) s = fmaf(gx[b * CG + c], gWsc[p * CG + c], s);
  hg[p * 32 + b] = s;
}

__global__ __launch_bounds__(256) void k_gln(
    const float* __restrict__ hg, const float* __restrict__ glng,
    const float* __restrict__ glnb, float* __restrict__ gnorm) {
  __shared__ float rb[4];
  int b = blockIdx.x;
  int tid = threadIdx.x;
  float v0 = hg[tid * 32 + b];
  float v1 = hg[(tid + 256) * 32 + b];
  float s = block_sum(v0 + v1, rb);
  float s2 = block_sum(fmaf(v0, v0, v1 * v1), rb);
  float mu = s * (1.f / MI);
  float var = s2 * (1.f / MI) - mu * mu;
  float rstd = rsqrtf(var + EPS);
  float L0 = fmaf((v0 - mu) * rstd, glng[tid], glnb[tid]);
  float L1 = fmaf((v1 - mu) * rstd, glng[tid + 256], glnb[tid + 256]);
  float n2 = block_sum(fmaf(L0, L0, L1 * L1), rb);
  float inv = rsqrtf(n2);
  gnorm[b * MI + tid] = L0 * inv;
  gnorm[b * MI + tid + 256] = L1 * inv;
}

// ---------------- 6: U[n][row] = inv_norm[row] * <g_n, L[row]> --------------
// g staged in LDS with per-row rotation swizzle (bank-conflict-free, no pad)
__global__ __launch_bounds__(256) void k_u(
    const float* __restrict__ L, const float* __restrict__ inv_norm,
    const float* __restrict__ g, float* __restrict__ U) {
  __shared__ float gs[32][512];  // 64KB, gs[n][(d+n)&511] = g[n][d]
  const int r0 = blockIdx.x * 16, tid = threadIdx.x;
#pragma unroll
  for (int i = 0; i < 64; i++) {
    int idx = tid + i * 256;
    int n = idx >> 9, d = idx & 511;
    gs[n][(d + n) & 511] = g[idx];
  }
  __syncthreads();
  const int n = tid & 31, rs = tid >> 5;
#pragma unroll
  for (int rr = rs; rr < 16; rr += 8) {
    const int row = r0 + rr;
    const float4* L4 = (const float4*)(L + (size_t)row * 512);
    float acc = 0.f;
    for (int d4 = 0; d4 < 128; d4++) {
      float4 lv = L4[d4];
      int dd = d4 * 4;
      acc = fmaf(lv.x, gs[n][(dd + n) & 511], acc);
      acc = fmaf(lv.y, gs[n][(dd + 1 + n) & 511], acc);
      acc = fmaf(lv.z, gs[n][(dd + 2 + n) & 511], acc);
      acc = fmaf(lv.w, gs[n][(dd + 3 + n) & 511], acc);
    }
    U[(size_t)n * NPOS + row] = acc * inv_norm[row];
  }
}

// ---------------- 7: per-row masked max & sumexp ----------------------------
__global__ __launch_bounds__(256) void k_rowstats(
    const float* __restrict__ U, float* __restrict__ row_max, float* __restrict__ row_se) {
  __shared__ float sm[NPOS];  // 32 KB
  __shared__ float rb[4];
  const int n = blockIdx.x;
  const int tid = threadIdx.x;
  const float* row = U + (size_t)n * NPOS;
  float mx = -1e30f;
  for (int i = tid; i < NPOS; i += 256) {
    int m = i >> 8;
    float v = (m == n) ? -1e30f : row[i];
    sm[i] = v;
    mx = fmaxf(mx, v);
  }
  mx = block_max(mx, rb);
  float s = 0.f;
  for (int i = tid; i < NPOS; i += 256) s += expf(sm[i] - mx);
  s = block_sum(s, rb);
  if (tid == 0) {
    row_max[n] = mx;
    row_se[n] = s;
  }
}

// ---------------- 8: loss = mean(lse - u_p) ---------------------------------
__global__ __launch_bounds__(256) void k_loss(
    const float* __restrict__ U, const float* __restrict__ row_max,
    const float* __restrict__ row_se, float* __restrict__ out) {
  __shared__ float rb[4];
  const int tid = threadIdx.x;
  float s = 0.f;
  for (int i = tid; i < NPOS; i += 256) {
    int n = i >> 8, t = i & 255;
    float up = U[(size_t)n * NPOS + n * T + t] * (1.f / TEMP);
    float rm = row_max[n], rs = row_se[n];
    float mx = fmaxf(up, rm);
    float lse = mx + logf(expf(up - mx) + rs * expf(rm - mx));
    s += lse - up;
  }
  s = block_sum(s, rb);
  if (tid == 0) out[0] = s * (1.f / NPOS);
}

extern "C" void kernel_launch(void* const* d_in, const int* in_sizes, int n_in,
                              void* d_out, int out_size, void* d_ws, size_t ws_size,
                              hipStream_t stream) {
  (void)in_sizes; (void)n_in; (void)out_size; (void)ws_size;
  const float* x    = (const float*)d_in[0];
  const float* gx   = (const float*)d_in[1];
  const float* lW1  = (const float*)d_in[2];
  const float* lg1  = (const float*)d_in[3];
  const float* lb1  = (const float*)d_in[4];
  const float* lW2  = (const float*)d_in[5];
  const float* lb2  = (const float*)d_in[6];
  const float* lWs  = (const float*)d_in[7];
  const float* llng = (const float*)d_in[8];
  const float* llnb = (const float*)d_in[9];
  const float* gW1  = (const float*)d_in[10];
  const float* gg1  = (const float*)d_in[11];
  const float* gb1  = (const float*)d_in[12];
  const float* gW2  = (const float*)d_in[13];
  const float* gb2  = (const float*)d_in[14];
  const float* gWs  = (const float*)d_in[15];
  const float* glng = (const float*)d_in[16];
  const float* glnb = (const float*)d_in[17];

  // ---- workspace layout (byte offsets; total ~46.4 MB, aliased) ----
  char* wsb = (char*)d_ws;
  unsigned short* xT  = (unsigned short*)(wsb);             // [8192][1536] bf16, 25165824 B
  unsigned short* vv  = (unsigned short*)(wsb);             // alias (xT dead): [8192][512] bf16
  float* hb           = (float*)(wsb + 8388608);            // alias: [8192][512] f32
  unsigned short* Wc  = (unsigned short*)(wsb + 25165824);  // [1024][1536] bf16
  float* U            = (float*)(wsb + 25165824);           // alias (Wc dead): [32][8192] f32
  unsigned short* W2b = (unsigned short*)(wsb + 28311552);  // [512][512] bf16
  unsigned short* y1u = (unsigned short*)(wsb + 28835840);  // [8192][512] bf16
  unsigned short* ysb = (unsigned short*)(wsb + 37224448);  // [8192][512] bf16
  float* ps           = (float*)(wsb + 45613056);           // [128][512]
  float* ps2          = (float*)(wsb + 45875200);           // [128][512]
  float* scl          = (float*)(wsb + 46137344);
  float* shf          = (float*)(wsb + 46139392);
  float* inv_norm     = (float*)(wsb + 46141440);           // [8192]
  float* y1g          = (float*)(wsb + 46174208);           // [512][32]
  float* gscale       = (float*)(wsb + 46239744);
  float* gshift       = (float*)(wsb + 46241792);
  float* hg           = (float*)(wsb + 46243840);           // [512][32]
  float* gnorm        = (float*)(wsb + 46309376);           // [32][512]
  float* rmax         = (float*)(wsb + 46374912);
  float* rse          = (float*)(wsb + 46375040);

  k_castw<<<dim3(1792), 256, 0, stream>>>(lW1, lWs, lW2, Wc, W2b);
  k_transpose<<<dim3(4, 24, 32), 256, 0, stream>>>(x, xT);
  k_gemm1<<<dim3(64, 8), 256, 0, stream>>>(xT, Wc, y1u, ysb);
  k_bnstat1<<<dim3(128), 256, 0, stream>>>(y1u, ps, ps2);
  k_bnstat2<<<dim3(2), 256, 0, stream>>>(ps, ps2, lg1, lb1, scl, shf);
  k_bnapply<<<dim3(4096), 256, 0, stream>>>(y1u, scl, shf, vv);
  k_gemm2<<<dim3(64, 4), 256, 0, stream>>>(vv, W2b, lb2, ysb, hb);
  k_ln<<<dim3(8192), 256, 0, stream>>>(hb, llng, llnb, inv_norm);
  k_gnet1<<<dim3(64), 256, 0, stream>>>(gx, gW1, y1g);
  k_gbn<<<dim3(2), 256, 0, stream>>>(y1g, gg1, gb1, gscale, gshift);
  k_gnet2<<<dim3(64), 256, 0, stream>>>(y1g, gscale, gshift, gW2, gb2, gx, gWs, hg);
  k_gln<<<dim3(32), 256, 0, stream>>>(hg, glng, glnb, gnorm);
  k_u<<<dim3(512), 256, 0, stream>>>(hb, inv_norm, gnorm, U);
  k_rowstats<<<dim3(32), 256, 0, stream>>>(U, rmax, rse);
  k_loss<<<dim3(1), 256, 0, stream>>>(U, rmax, rse, (float*)d_out);
}

// Round 3
// 263.926 us; speedup vs baseline: 2.6038x; 1.1292x over previous
//
#include <hip/hip_runtime.h>

#define B 32
#define CL 1536
#define CG 192
#define T 256
#define MI 512
#define NPOS 8192   /* B*T */
#define EPS 1e-5f
#define TEMP 0.07f

typedef __attribute__((ext_vector_type(8))) __bf16 bf16x8;
typedef __attribute__((ext_vector_type(4))) float f32x4;

__device__ __forceinline__ unsigned short f2bf(float f) {
  union { float f; unsigned u; } v; v.f = f;
  unsigned r = v.u + 0x7FFFu + ((v.u >> 16) & 1u);
  return (unsigned short)(r >> 16);
}
__device__ __forceinline__ float bf2f(unsigned short h) {
  union { unsigned u; float f; } v; v.u = ((unsigned)h) << 16;
  return v.f;
}

__device__ __forceinline__ float wave_sum(float v) {
#pragma unroll
  for (int off = 32; off > 0; off >>= 1) v += __shfl_xor(v, off, 64);
  return v;
}
__device__ __forceinline__ float wave_max(float v) {
#pragma unroll
  for (int off = 32; off > 0; off >>= 1) v = fmaxf(v, __shfl_xor(v, off, 64));
  return v;
}
__device__ __forceinline__ float block_sum(float v, float* rb) {
  v = wave_sum(v);
  __syncthreads();
  if ((threadIdx.x & 63) == 0) rb[threadIdx.x >> 6] = v;
  __syncthreads();
  return rb[0] + rb[1] + rb[2] + rb[3];
}
__device__ __forceinline__ float block_max(float v, float* rb) {
  v = wave_max(v);
  __syncthreads();
  if ((threadIdx.x & 63) == 0) rb[threadIdx.x >> 6] = v;
  __syncthreads();
  return fmaxf(fmaxf(rb[0], rb[1]), fmaxf(rb[2], rb[3]));
}

// ============ 1: prep = weight casts + x transpose + gnet1 ==================
// blocks [0,1792): cast W1||Ws -> Wc, W2 -> W2b
// blocks [1792,4864): x [b][c][t] f32 -> xT [b*T+t][c] bf16
// blocks [4864,4928): y1g = gx . gW1^T  (global net conv1)
__global__ __launch_bounds__(256) void k_prep(
    const float* __restrict__ x, const float* __restrict__ lW1,
    const float* __restrict__ lWs, const float* __restrict__ lW2,
    const float* __restrict__ gx, const float* __restrict__ gW1,
    unsigned short* __restrict__ xT, unsigned short* __restrict__ Wc,
    unsigned short* __restrict__ W2b, float* __restrict__ y1g) {
  __shared__ float xs[64][65];
  const int bi = blockIdx.x, tid = threadIdx.x;
  if (bi < 1792) {
    int idx = (bi * 256 + tid) * 4;
    const float* src; unsigned short* dst;
    if (idx < 786432) { src = lW1 + idx; dst = Wc + idx; }
    else if (idx < 1572864) { src = lWs + (idx - 786432); dst = Wc + idx; }
    else { src = lW2 + (idx - 1572864); dst = W2b + (idx - 1572864); }
    float4 v = *(const float4*)src;
    ushort4 o = {f2bf(v.x), f2bf(v.y), f2bf(v.z), f2bf(v.w)};
    *(ushort4*)dst = o;
  } else if (bi < 4864) {
    int bi2 = bi - 1792;
    int b = bi2 / 96, rem = bi2 - b * 96;
    int c0 = (rem >> 2) * 64, t0 = (rem & 3) * 64;
    const float* xb = x + ((size_t)b * CL + c0) * T + t0;
#pragma unroll
    for (int i = 0; i < 16; i++) {
      int idx = tid + i * 256, c = idx >> 6, t = idx & 63;
      xs[c][t] = xb[(size_t)c * T + t];
    }
    __syncthreads();
    unsigned short* ob = xT + ((size_t)b * T + t0) * CL + c0;
#pragma unroll
    for (int i = 0; i < 8; i++) {
      int idx = tid + i * 256, t = idx >> 5, k = (idx & 31) * 2;
      ushort2 v = {f2bf(xs[k][t]), f2bf(xs[k + 1][t])};
      *(ushort2*)&ob[(size_t)t * CL + k] = v;
    }
  } else {
    int idx = (bi - 4864) * 256 + tid;
    int b = idx & 31, o = idx >> 5;
    float s = 0.f;
    for (int c = 0; c < CG; c++) s = fmaf(gx[b * CG + c], gW1[o * CG + c], s);
    y1g[o * 32 + b] = s;
  }
}

// ============ 2: gemm1 (dual, MFMA) + BN-stat atomics + gbn piggyback =======
__global__ __launch_bounds__(256) void k_gemm1(
    const unsigned short* __restrict__ xT, const unsigned short* __restrict__ Wc,
    unsigned short* __restrict__ y1u, unsigned short* __restrict__ ysb,
    float* __restrict__ bsum, float* __restrict__ bsq,
    const float* __restrict__ y1g, const float* __restrict__ gg1,
    const float* __restrict__ gb1, float* __restrict__ gscale,
    float* __restrict__ gshift) {
  const int tid = threadIdx.x;
  if (blockIdx.x >= 512) {  // gbn: BN stats for global net (512 channels)
    int o = (blockIdx.x - 512) * 256 + tid;
    float s = 0.f, s2 = 0.f;
    for (int b = 0; b < 32; b++) {
      float v = y1g[o * 32 + b];
      s += v; s2 = fmaf(v, v, s2);
    }
    float mu = s * (1.f / 32.f);
    float var = s2 * (1.f / 32.f) - mu * mu;
    float sc = gg1[o] * rsqrtf(var + EPS);
    gscale[o] = sc;
    gshift[o] = gb1[o] - mu * sc;
    return;
  }
  __shared__ __align__(16) unsigned short As[128][32];
  __shared__ __align__(16) unsigned short Bs[128][32];
  __shared__ float csum[128], csq[128];
  const int w = tid >> 6, lane = tid & 63;
  const int m0 = (blockIdx.x & 63) * 128, o0 = (blockIdx.x >> 6) * 128;
  const int sr = lane >> 2, sc = (lane & 3) * 8;
  const int wm = w & 1, wn = w >> 1;
  const int lm = lane & 15, q = lane >> 4;
  f32x4 acc[4][4];
#pragma unroll
  for (int i = 0; i < 4; i++)
#pragma unroll
    for (int j = 0; j < 4; j++) acc[i][j] = f32x4{0.f, 0.f, 0.f, 0.f};
  if (tid < 128) { csum[tid] = 0.f; csq[tid] = 0.f; }

  const unsigned short* pa0 = xT + (size_t)(m0 + w * 32 + sr) * CL + sc;
  const unsigned short* pa1 = pa0 + (size_t)16 * CL;
  const unsigned short* pb0 = Wc + (size_t)(o0 + w * 32 + sr) * CL + sc;
  const unsigned short* pb1 = pb0 + (size_t)16 * CL;
  for (int c0 = 0; c0 < CL; c0 += 32) {
    __builtin_amdgcn_global_load_lds(
        (const __attribute__((address_space(1))) void*)(pa0 + c0),
        (__attribute__((address_space(3))) void*)&As[w * 32][0], 16, 0, 0);
    __builtin_amdgcn_global_load_lds(
        (const __attribute__((address_space(1))) void*)(pa1 + c0),
        (__attribute__((address_space(3))) void*)&As[w * 32 + 16][0], 16, 0, 0);
    __builtin_amdgcn_global_load_lds(
        (const __attribute__((address_space(1))) void*)(pb0 + c0),
        (__attribute__((address_space(3))) void*)&Bs[w * 32][0], 16, 0, 0);
    __builtin_amdgcn_global_load_lds(
        (const __attribute__((address_space(1))) void*)(pb1 + c0),
        (__attribute__((address_space(3))) void*)&Bs[w * 32 + 16][0], 16, 0, 0);
    __syncthreads();
    bf16x8 af[4], bfr[4];
#pragma unroll
    for (int mi = 0; mi < 4; mi++)
      af[mi] = *(const bf16x8*)&As[wm * 64 + mi * 16 + lm][q * 8];
#pragma unroll
    for (int ni = 0; ni < 4; ni++)
      bfr[ni] = *(const bf16x8*)&Bs[wn * 64 + ni * 16 + lm][q * 8];
#pragma unroll
    for (int mi = 0; mi < 4; mi++)
#pragma unroll
      for (int ni = 0; ni < 4; ni++)
        acc[mi][ni] = __builtin_amdgcn_mfma_f32_16x16x32_bf16(
            af[mi], bfr[ni], acc[mi][ni], 0, 0, 0);
    __syncthreads();
  }
  const int row0 = m0 + wm * 64 + q * 4;
  const bool isY1 = (o0 < 512);
  unsigned short* dst = isY1 ? y1u : ysb;
  const int ob = isY1 ? o0 : o0 - 512;
#pragma unroll
  for (int mi = 0; mi < 4; mi++)
#pragma unroll
    for (int ni = 0; ni < 4; ni++) {
      int oc = ob + wn * 64 + ni * 16 + lm;
#pragma unroll
      for (int r = 0; r < 4; r++)
        dst[(size_t)(row0 + mi * 16 + r) * 512 + oc] = f2bf(acc[mi][ni][r]);
    }
  if (isY1) {  // BN partial stats: LDS reduce then one global atomic per col
#pragma unroll
    for (int ni = 0; ni < 4; ni++) {
      float s = 0.f, s2 = 0.f;
#pragma unroll
      for (int mi = 0; mi < 4; mi++)
#pragma unroll
        for (int r = 0; r < 4; r++) {
          float v = acc[mi][ni][r];
          s += v; s2 = fmaf(v, v, s2);
        }
      int col = wn * 64 + ni * 16 + lm;
      atomicAdd(&csum[col], s);
      atomicAdd(&csq[col], s2);
    }
    __syncthreads();
    if (tid < 128) {
      atomicAdd(&bsum[o0 + tid], csum[tid]);
      atomicAdd(&bsq[o0 + tid], csq[tid]);
    }
  }
}

// ============ 3: bnapply (v = bf16(relu(bn(y1)))) + gnet2 piggyback =========
__global__ __launch_bounds__(256) void k_bnapp(
    const unsigned short* __restrict__ y1u, const float* __restrict__ bsum,
    const float* __restrict__ bsq, const float* __restrict__ lg1,
    const float* __restrict__ lb1, unsigned short* __restrict__ vv,
    const float* __restrict__ y1g, const float* __restrict__ gscale,
    const float* __restrict__ gshift, const float* __restrict__ gW2,
    const float* __restrict__ gb2, const float* __restrict__ gx,
    const float* __restrict__ gWsc, float* __restrict__ hg) {
  const int bi = blockIdx.x, tid = threadIdx.x;
  if (bi < 4096) {
    int idx = (bi * 256 + tid) * 4;
    int o = idx & 511;
    ushort4 in = *(const ushort4*)&y1u[idx];
    ushort4 out;
    float iv[4] = {bf2f(in.x), bf2f(in.y), bf2f(in.z), bf2f(in.w)};
    unsigned short ov[4];
#pragma unroll
    for (int j = 0; j < 4; j++) {
      float mu = bsum[o + j] * (1.f / NPOS);
      float var = bsq[o + j] * (1.f / NPOS) - mu * mu;
      float sc = lg1[o + j] * rsqrtf(var + EPS);
      float sh = lb1[o + j] - mu * sc;
      ov[j] = f2bf(fmaxf(fmaf(iv[j], sc, sh), 0.f));
    }
    out.x = ov[0]; out.y = ov[1]; out.z = ov[2]; out.w = ov[3];
    *(ushort4*)&vv[idx] = out;
  } else {  // gnet2
    int idx = (bi - 4096) * 256 + tid;
    int b = idx & 31, p = idx >> 5;
    float s = gb2[p];
    for (int o = 0; o < MI; o++) {
      float v = fmaxf(fmaf(y1g[o * 32 + b], gscale[o], gshift[o]), 0.f);
      s = fmaf(v, gW2[(size_t)p * MI + o], s);
    }
    for (int c = 0; c < CG; c++) s = fmaf(gx[b * CG + c], gWsc[p * CG + c], s);
    hg[p * 32 + b] = s;
  }
}

// ============ 4: gemm2 (h = v.W2^T + b2 + ys, bf16 out) + gln piggyback =====
__global__ __launch_bounds__(256) void k_gemm2(
    const unsigned short* __restrict__ vv, const unsigned short* __restrict__ W2b,
    const float* __restrict__ b2, const unsigned short* __restrict__ ysb,
    unsigned short* __restrict__ hb16,
    const float* __restrict__ hg, const float* __restrict__ glng,
    const float* __restrict__ glnb, unsigned short* __restrict__ gnormb) {
  __shared__ __align__(16) unsigned short As[128][32];
  __shared__ __align__(16) unsigned short Bs[128][32];
  __shared__ float rb[4];
  const int tid = threadIdx.x;
  if (blockIdx.x >= 256) {  // gln: LayerNorm + normalize global embeddings
    int b = blockIdx.x - 256;
    float v0 = hg[tid * 32 + b];
    float v1 = hg[(tid + 256) * 32 + b];
    float s = block_sum(v0 + v1, rb);
    float s2 = block_sum(fmaf(v0, v0, v1 * v1), rb);
    float mu = s * (1.f / MI);
    float var = s2 * (1.f / MI) - mu * mu;
    float rstd = rsqrtf(var + EPS);
    float L0 = fmaf((v0 - mu) * rstd, glng[tid], glnb[tid]);
    float L1 = fmaf((v1 - mu) * rstd, glng[tid + 256], glnb[tid + 256]);
    float n2 = block_sum(fmaf(L0, L0, L1 * L1), rb);
    float inv = rsqrtf(n2);
    gnormb[b * MI + tid] = f2bf(L0 * inv);
    gnormb[b * MI + tid + 256] = f2bf(L1 * inv);
    return;
  }
  const int w = tid >> 6, lane = tid & 63;
  const int m0 = (blockIdx.x & 63) * 128, p0 = (blockIdx.x >> 6) * 128;
  const int sr = lane >> 2, sc = (lane & 3) * 8;
  const int wm = w & 1, wn = w >> 1;
  const int lm = lane & 15, q = lane >> 4;
  f32x4 acc[4][4];
#pragma unroll
  for (int i = 0; i < 4; i++)
#pragma unroll
    for (int j = 0; j < 4; j++) acc[i][j] = f32x4{0.f, 0.f, 0.f, 0.f};

  const unsigned short* pa0 = vv + (size_t)(m0 + w * 32 + sr) * 512 + sc;
  const unsigned short* pa1 = pa0 + (size_t)16 * 512;
  const unsigned short* pb0 = W2b + (size_t)(p0 + w * 32 + sr) * 512 + sc;
  const unsigned short* pb1 = pb0 + (size_t)16 * 512;
  for (int c0 = 0; c0 < 512; c0 += 32) {
    __builtin_amdgcn_global_load_lds(
        (const __attribute__((address_space(1))) void*)(pa0 + c0),
        (__attribute__((address_space(3))) void*)&As[w * 32][0], 16, 0, 0);
    __builtin_amdgcn_global_load_lds(
        (const __attribute__((address_space(1))) void*)(pa1 + c0),
        (__attribute__((address_space(3))) void*)&As[w * 32 + 16][0], 16, 0, 0);
    __builtin_amdgcn_global_load_lds(
        (const __attribute__((address_space(1))) void*)(pb0 + c0),
        (__attribute__((address_space(3))) void*)&Bs[w * 32][0], 16, 0, 0);
    __builtin_amdgcn_global_load_lds(
        (const __attribute__((address_space(1))) void*)(pb1 + c0),
        (__attribute__((address_space(3))) void*)&Bs[w * 32 + 16][0], 16, 0, 0);
    __syncthreads();
    bf16x8 af[4], bfr[4];
#pragma unroll
    for (int mi = 0; mi < 4; mi++)
      af[mi] = *(const bf16x8*)&As[wm * 64 + mi * 16 + lm][q * 8];
#pragma unroll
    for (int ni = 0; ni < 4; ni++)
      bfr[ni] = *(const bf16x8*)&Bs[wn * 64 + ni * 16 + lm][q * 8];
#pragma unroll
    for (int mi = 0; mi < 4; mi++)
#pragma unroll
      for (int ni = 0; ni < 4; ni++)
        acc[mi][ni] = __builtin_amdgcn_mfma_f32_16x16x32_bf16(
            af[mi], bfr[ni], acc[mi][ni], 0, 0, 0);
    __syncthreads();
  }
  const int row0 = m0 + wm * 64 + q * 4;
#pragma unroll
  for (int ni = 0; ni < 4; ni++) {
    int p = p0 + wn * 64 + ni * 16 + lm;
    float bias = b2[p];
#pragma unroll
    for (int mi = 0; mi < 4; mi++)
#pragma unroll
      for (int r = 0; r < 4; r++) {
        size_t off = (size_t)(row0 + mi * 16 + r) * 512 + p;
        hb16[off] = f2bf(acc[mi][ni][r] + bias + bf2f(ysb[off]));
      }
  }
}

// ============ 5: LayerNorm per row -> L_hat bf16 (pre-divided by ||L||) =====
__global__ __launch_bounds__(256) void k_ln(
    const unsigned short* __restrict__ hb16, const float* __restrict__ lng,
    const float* __restrict__ lnb, unsigned short* __restrict__ Lb) {
  __shared__ float rb[4];
  const int r = blockIdx.x, tid = threadIdx.x;
  const unsigned short* row = hb16 + (size_t)r * 512;
  float v0 = bf2f(row[tid]), v1 = bf2f(row[tid + 256]);
  float s = block_sum(v0 + v1, rb);
  float s2 = block_sum(fmaf(v0, v0, v1 * v1), rb);
  float mu = s * (1.f / MI);
  float var = s2 * (1.f / MI) - mu * mu;
  float rstd = rsqrtf(var + EPS);
  float L0 = fmaf((v0 - mu) * rstd, lng[tid], lnb[tid]);
  float L1 = fmaf((v1 - mu) * rstd, lng[tid + 256], lnb[tid + 256]);
  float n2 = block_sum(fmaf(L0, L0, L1 * L1), rb);
  float inv = rsqrtf(n2);
  unsigned short* orow = Lb + (size_t)r * 512;
  orow[tid] = f2bf(L0 * inv);
  orow[tid + 256] = f2bf(L1 * inv);
}

// ============ 6: U = gnorm (32x512) x Lhat^T (8192x512) via MFMA ============
__global__ __launch_bounds__(256) void k_u(
    const unsigned short* __restrict__ g, const unsigned short* __restrict__ Lb,
    float* __restrict__ U) {
  const int tid = threadIdx.x;
  const int w = tid >> 6, lane = tid & 63;
  const int lm = lane & 15, q = lane >> 4;
  const int rbase = blockIdx.x * 128 + w * 32;
  f32x4 acc[2][2];
#pragma unroll
  for (int i = 0; i < 2; i++)
#pragma unroll
    for (int j = 0; j < 2; j++) acc[i][j] = f32x4{0.f, 0.f, 0.f, 0.f};
  for (int k0 = 0; k0 < 512; k0 += 32) {
    bf16x8 af[2], bfr[2];
#pragma unroll
    for (int mi = 0; mi < 2; mi++)
      af[mi] = *(const bf16x8*)&g[(size_t)(mi * 16 + lm) * 512 + k0 + q * 8];
#pragma unroll
    for (int ni = 0; ni < 2; ni++)
      bfr[ni] = *(const bf16x8*)&Lb[(size_t)(rbase + ni * 16 + lm) * 512 + k0 + q * 8];
#pragma unroll
    for (int mi = 0; mi < 2; mi++)
#pragma unroll
      for (int ni = 0; ni < 2; ni++)
        acc[mi][ni] = __builtin_amdgcn_mfma_f32_16x16x32_bf16(
            af[mi], bfr[ni], acc[mi][ni], 0, 0, 0);
  }
#pragma unroll
  for (int mi = 0; mi < 2; mi++)
#pragma unroll
    for (int ni = 0; ni < 2; ni++) {
      int row = rbase + ni * 16 + lm;
#pragma unroll
      for (int r = 0; r < 4; r++) {
        int gi = mi * 16 + q * 4 + r;
        U[(size_t)gi * NPOS + row] = acc[mi][ni][r];
      }
    }
}

// ============ 7: per-row masked max & sumexp ================================
__global__ __launch_bounds__(256) void k_rowstats(
    const float* __restrict__ U, float* __restrict__ row_max, float* __restrict__ row_se) {
  __shared__ float sm[NPOS];
  __shared__ float rb[4];
  const int n = blockIdx.x, tid = threadIdx.x;
  const float* row = U + (size_t)n * NPOS;
  float mx = -1e30f;
  for (int i = tid; i < NPOS; i += 256) {
    int m = i >> 8;
    float v = (m == n) ? -1e30f : row[i];
    sm[i] = v;
    mx = fmaxf(mx, v);
  }
  mx = block_max(mx, rb);
  float s = 0.f;
  for (int i = tid; i < NPOS; i += 256) s += expf(sm[i] - mx);
  s = block_sum(s, rb);
  if (tid == 0) { row_max[n] = mx; row_se[n] = s; }
}

// ============ 8: loss = mean(lse - u_p) =====================================
__global__ __launch_bounds__(256) void k_loss(
    const float* __restrict__ U, const float* __restrict__ row_max,
    const float* __restrict__ row_se, float* __restrict__ out) {
  __shared__ float rb[4];
  const int tid = threadIdx.x;
  float s = 0.f;
  for (int i = tid; i < NPOS; i += 256) {
    int n = i >> 8, t = i & 255;
    float up = U[(size_t)n * NPOS + n * T + t] * (1.f / TEMP);
    float rm = row_max[n], rs = row_se[n];
    float mx = fmaxf(up, rm);
    float lse = mx + logf(expf(up - mx) + rs * expf(rm - mx));
    s += lse - up;
  }
  s = block_sum(s, rb);
  if (tid == 0) out[0] = s * (1.f / NPOS);
}

extern "C" void kernel_launch(void* const* d_in, const int* in_sizes, int n_in,
                              void* d_out, int out_size, void* d_ws, size_t ws_size,
                              hipStream_t stream) {
  (void)in_sizes; (void)n_in; (void)out_size; (void)ws_size;
  const float* x    = (const float*)d_in[0];
  const float* gx   = (const float*)d_in[1];
  const float* lW1  = (const float*)d_in[2];
  const float* lg1  = (const float*)d_in[3];
  const float* lb1  = (const float*)d_in[4];
  const float* lW2  = (const float*)d_in[5];
  const float* lb2  = (const float*)d_in[6];
  const float* lWs  = (const float*)d_in[7];
  const float* llng = (const float*)d_in[8];
  const float* llnb = (const float*)d_in[9];
  const float* gW1  = (const float*)d_in[10];
  const float* gg1  = (const float*)d_in[11];
  const float* gb1  = (const float*)d_in[12];
  const float* gW2  = (const float*)d_in[13];
  const float* gb2  = (const float*)d_in[14];
  const float* gWs  = (const float*)d_in[15];
  const float* glng = (const float*)d_in[16];
  const float* glnb = (const float*)d_in[17];

  // ---- workspace (256 MiB available; ~72 MB used, no aliasing) ----
  char* wsb = (char*)d_ws;
  unsigned short* xT     = (unsigned short*)(wsb);             // [8192][1536] bf16
  unsigned short* Wc     = (unsigned short*)(wsb + 25165824);  // [1024][1536] bf16
  unsigned short* W2b    = (unsigned short*)(wsb + 28311552);  // [512][512] bf16
  unsigned short* y1u    = (unsigned short*)(wsb + 28835840);  // [8192][512] bf16
  unsigned short* ysb    = (unsigned short*)(wsb + 37224448);  // [8192][512] bf16
  unsigned short* vv     = (unsigned short*)(wsb + 45613056);  // [8192][512] bf16
  unsigned short* hb16   = (unsigned short*)(wsb + 54001664);  // [8192][512] bf16
  unsigned short* Lb     = (unsigned short*)(wsb + 62390272);  // [8192][512] bf16
  float* U               = (float*)(wsb + 70778880);           // [32][8192] f32
  float* bsum            = (float*)(wsb + 71827456);           // [512]
  float* bsq             = (float*)(wsb + 71829504);           // [512]
  float* y1g             = (float*)(wsb + 71831552);           // [512][32]
  float* gscale          = (float*)(wsb + 71897088);           // [512]
  float* gshift          = (float*)(wsb + 71899136);           // [512]
  float* hg              = (float*)(wsb + 71901184);           // [512][32]
  unsigned short* gnormb = (unsigned short*)(wsb + 71966720);  // [32][512] bf16
  float* rmax            = (float*)(wsb + 71999488);           // [32]
  float* rse             = (float*)(wsb + 71999616);           // [32]

  hipMemsetAsync(bsum, 0, 4096, stream);  // zero bsum+bsq (adjacent)
  k_prep<<<dim3(4928), 256, 0, stream>>>(x, lW1, lWs, lW2, gx, gW1, xT, Wc, W2b, y1g);
  k_gemm1<<<dim3(514), 256, 0, stream>>>(xT, Wc, y1u, ysb, bsum, bsq,
                                         y1g, gg1, gb1, gscale, gshift);
  k_bnapp<<<dim3(4160), 256, 0, stream>>>(y1u, bsum, bsq, lg1, lb1, vv,
                                          y1g, gscale, gshift, gW2, gb2, gx, gWs, hg);
  k_gemm2<<<dim3(288), 256, 0, stream>>>(vv, W2b, lb2, ysb, hb16,
                                         hg, glng, glnb, gnormb);
  k_ln<<<dim3(8192), 256, 0, stream>>>(hb16, llng, llnb, Lb);
  k_u<<<dim3(64), 256, 0, stream>>>(gnormb, Lb, U);
  k_rowstats<<<dim3(32), 256, 0, stream>>>(U, rmax, rse);
  k_loss<<<dim3(1), 256, 0, stream>>>(U, rmax, rse, (float*)d_out);
}

// Round 4
// 248.798 us; speedup vs baseline: 2.7622x; 1.0608x over previous
//
#include <hip/hip_runtime.h>

#define B 32
#define CL 1536
#define CG 192
#define T 256
#define MI 512
#define NPOS 8192   /* B*T */
#define EPS 1e-5f
#define TEMP 0.07f

typedef __attribute__((ext_vector_type(8))) __bf16 bf16x8;
typedef __attribute__((ext_vector_type(4))) float f32x4;

__device__ __forceinline__ unsigned short f2bf(float f) {
  union { float f; unsigned u; } v; v.f = f;
  unsigned r = v.u + 0x7FFFu + ((v.u >> 16) & 1u);
  return (unsigned short)(r >> 16);
}
__device__ __forceinline__ float bf2f(unsigned short h) {
  union { unsigned u; float f; } v; v.u = ((unsigned)h) << 16;
  return v.f;
}

__device__ __forceinline__ float wave_sum(float v) {
#pragma unroll
  for (int off = 32; off > 0; off >>= 1) v += __shfl_xor(v, off, 64);
  return v;
}
__device__ __forceinline__ float wave_max(float v) {
#pragma unroll
  for (int off = 32; off > 0; off >>= 1) v = fmaxf(v, __shfl_xor(v, off, 64));
  return v;
}
// 256-thread block reductions
__device__ __forceinline__ float block_sum(float v, float* rb) {
  v = wave_sum(v);
  __syncthreads();
  if ((threadIdx.x & 63) == 0) rb[threadIdx.x >> 6] = v;
  __syncthreads();
  return rb[0] + rb[1] + rb[2] + rb[3];
}
__device__ __forceinline__ float block_max(float v, float* rb) {
  v = wave_max(v);
  __syncthreads();
  if ((threadIdx.x & 63) == 0) rb[threadIdx.x >> 6] = v;
  __syncthreads();
  return fmaxf(fmaxf(rb[0], rb[1]), fmaxf(rb[2], rb[3]));
}
// 128-thread block reduction
__device__ __forceinline__ float bs128(float v, float* rb) {
  v = wave_sum(v);
  __syncthreads();
  if ((threadIdx.x & 63) == 0) rb[threadIdx.x >> 6] = v;
  __syncthreads();
  return rb[0] + rb[1];
}

// ============ 1: prep = weight casts + x transpose + gnet1 + zero bn ========
__global__ __launch_bounds__(256) void k_prep(
    const float* __restrict__ x, const float* __restrict__ lW1,
    const float* __restrict__ lWs, const float* __restrict__ lW2,
    const float* __restrict__ gx, const float* __restrict__ gW1,
    unsigned short* __restrict__ xT, unsigned short* __restrict__ Wc,
    unsigned short* __restrict__ W2b, float* __restrict__ y1g,
    float* __restrict__ bsum) {
  __shared__ float xs[64][65];
  const int bi = blockIdx.x, tid = threadIdx.x;
  if (bi < 1792) {
    int idx = (bi * 256 + tid) * 4;
    const float* src; unsigned short* dst;
    if (idx < 786432) { src = lW1 + idx; dst = Wc + idx; }
    else if (idx < 1572864) { src = lWs + (idx - 786432); dst = Wc + idx; }
    else { src = lW2 + (idx - 1572864); dst = W2b + (idx - 1572864); }
    float4 v = *(const float4*)src;
    ushort4 o = {f2bf(v.x), f2bf(v.y), f2bf(v.z), f2bf(v.w)};
    *(ushort4*)dst = o;
  } else if (bi < 4864) {
    int bi2 = bi - 1792;
    int b = bi2 / 96, rem = bi2 - b * 96;
    int c0 = (rem >> 2) * 64, t0 = (rem & 3) * 64;
    const float* xb = x + ((size_t)b * CL + c0) * T + t0;
#pragma unroll
    for (int i = 0; i < 16; i++) {
      int idx = tid + i * 256, c = idx >> 6, t = idx & 63;
      xs[c][t] = xb[(size_t)c * T + t];
    }
    __syncthreads();
    unsigned short* ob = xT + ((size_t)b * T + t0) * CL + c0;
#pragma unroll
    for (int i = 0; i < 8; i++) {
      int idx = tid + i * 256, t = idx >> 5, k = (idx & 31) * 2;
      ushort2 v = {f2bf(xs[k][t]), f2bf(xs[k + 1][t])};
      *(ushort2*)&ob[(size_t)t * CL + k] = v;
    }
  } else if (bi < 4928) {
    int idx = (bi - 4864) * 256 + tid;
    int b = idx & 31, o = idx >> 5;
    float s = 0.f;
    for (int c = 0; c < CG; c++) s = fmaf(gx[b * CG + c], gW1[o * CG + c], s);
    y1g[o * 32 + b] = s;
  } else {
    float4 z = {0.f, 0.f, 0.f, 0.f};
    ((float4*)bsum)[tid] = z;  // zeroes bsum[512] + bsq[512] (adjacent)
  }
}

// ============ 2: gemm1 dual MFMA, 128-thr blocks, BM=64 BN=128 BK=32 ========
// grid: 1024 GEMM blocks (m-tile = bi&127, n-tile = bi>>7) + 4 gbn blocks
__global__ __launch_bounds__(128, 4) void k_gemm1(
    const unsigned short* __restrict__ xT, const unsigned short* __restrict__ Wc,
    unsigned short* __restrict__ y1u, unsigned short* __restrict__ ysb,
    float* __restrict__ bsum, float* __restrict__ bsq,
    const float* __restrict__ y1g, const float* __restrict__ gg1,
    const float* __restrict__ gb1, float* __restrict__ gscale,
    float* __restrict__ gshift) {
  const int tid = threadIdx.x, bi = blockIdx.x;
  if (bi >= 1024) {  // gbn: BN stats for global net (512 channels, 4 blocks)
    int o = (bi - 1024) * 128 + tid;
    float s = 0.f, s2 = 0.f;
    for (int b = 0; b < 32; b++) {
      float v = y1g[o * 32 + b];
      s += v; s2 = fmaf(v, v, s2);
    }
    float mu = s * (1.f / 32.f);
    float var = s2 * (1.f / 32.f) - mu * mu;
    float sc = gg1[o] * rsqrtf(var + EPS);
    gscale[o] = sc;
    gshift[o] = gb1[o] - mu * sc;
    return;
  }
  __shared__ __align__(16) unsigned short As[64][32];
  __shared__ __align__(16) unsigned short Bs[128][32];
  __shared__ float ps[128], pq[128];
  const int w = tid >> 6, lane = tid & 63;
  const int m0 = (bi & 127) * 64, o0 = (bi >> 7) * 128;
  const int sr = lane >> 2, sc = (lane & 3) * 8;  // 16 rows per lds-instr
  const int lm = lane & 15, q = lane >> 4;
  f32x4 acc[4][4];
#pragma unroll
  for (int i = 0; i < 4; i++)
#pragma unroll
    for (int j = 0; j < 4; j++) acc[i][j] = f32x4{0.f, 0.f, 0.f, 0.f};

  const unsigned short* pa = xT + (size_t)(m0 + w * 32 + sr) * CL + sc;
  const unsigned short* pb = Wc + (size_t)(o0 + w * 64 + sr) * CL + sc;
  for (int k0 = 0; k0 < CL; k0 += 32) {
    __builtin_amdgcn_global_load_lds(
        (const __attribute__((address_space(1))) void*)(pa + k0),
        (__attribute__((address_space(3))) void*)&As[w * 32][0], 16, 0, 0);
    __builtin_amdgcn_global_load_lds(
        (const __attribute__((address_space(1))) void*)(pa + 16 * CL + k0),
        (__attribute__((address_space(3))) void*)&As[w * 32 + 16][0], 16, 0, 0);
    __builtin_amdgcn_global_load_lds(
        (const __attribute__((address_space(1))) void*)(pb + k0),
        (__attribute__((address_space(3))) void*)&Bs[w * 64][0], 16, 0, 0);
    __builtin_amdgcn_global_load_lds(
        (const __attribute__((address_space(1))) void*)(pb + 16 * CL + k0),
        (__attribute__((address_space(3))) void*)&Bs[w * 64 + 16][0], 16, 0, 0);
    __builtin_amdgcn_global_load_lds(
        (const __attribute__((address_space(1))) void*)(pb + 32 * CL + k0),
        (__attribute__((address_space(3))) void*)&Bs[w * 64 + 32][0], 16, 0, 0);
    __builtin_amdgcn_global_load_lds(
        (const __attribute__((address_space(1))) void*)(pb + 48 * CL + k0),
        (__attribute__((address_space(3))) void*)&Bs[w * 64 + 48][0], 16, 0, 0);
    __syncthreads();
    bf16x8 af[4], bfr[4];
#pragma unroll
    for (int mi = 0; mi < 4; mi++)
      af[mi] = *(const bf16x8*)&As[mi * 16 + lm][q * 8];
#pragma unroll
    for (int ni = 0; ni < 4; ni++)
      bfr[ni] = *(const bf16x8*)&Bs[w * 64 + ni * 16 + lm][q * 8];
#pragma unroll
    for (int mi = 0; mi < 4; mi++)
#pragma unroll
      for (int ni = 0; ni < 4; ni++)
        acc[mi][ni] = __builtin_amdgcn_mfma_f32_16x16x32_bf16(
            af[mi], bfr[ni], acc[mi][ni], 0, 0, 0);
    __syncthreads();
  }
  const int row0 = m0 + q * 4;
  const bool isY1 = (o0 < 512);
  unsigned short* dst = isY1 ? y1u : ysb;
  const int ob = isY1 ? o0 : o0 - 512;
#pragma unroll
  for (int mi = 0; mi < 4; mi++)
#pragma unroll
    for (int ni = 0; ni < 4; ni++) {
      int oc = ob + w * 64 + ni * 16 + lm;
#pragma unroll
      for (int r = 0; r < 4; r++)
        dst[(size_t)(row0 + mi * 16 + r) * 512 + oc] = f2bf(acc[mi][ni][r]);
    }
  if (isY1) {  // BN stats: in-register col sums + shuffle over q + 1 atomic/col
#pragma unroll
    for (int ni = 0; ni < 4; ni++) {
      float s = 0.f, s2 = 0.f;
#pragma unroll
      for (int mi = 0; mi < 4; mi++)
#pragma unroll
        for (int r = 0; r < 4; r++) {
          float v = acc[mi][ni][r];
          s += v; s2 = fmaf(v, v, s2);
        }
      s += __shfl_xor(s, 16, 64);  s2 += __shfl_xor(s2, 16, 64);
      s += __shfl_xor(s, 32, 64);  s2 += __shfl_xor(s2, 32, 64);
      if (q == 0) {  // lanes 0..15 hold full 64-row column sums
        int c = w * 64 + ni * 16 + lm;
        ps[c] = s; pq[c] = s2;
      }
    }
    __syncthreads();
    atomicAdd(&bsum[o0 + tid], ps[tid]);
    atomicAdd(&bsq[o0 + tid], pq[tid]);
  }
}

// ============ 3: bnapply (v = bf16(relu(bn(y1)))) + gnet2 piggyback =========
__global__ __launch_bounds__(256) void k_bnapp(
    const unsigned short* __restrict__ y1u, const float* __restrict__ bsum,
    const float* __restrict__ bsq, const float* __restrict__ lg1,
    const float* __restrict__ lb1, unsigned short* __restrict__ vv,
    const float* __restrict__ y1g, const float* __restrict__ gscale,
    const float* __restrict__ gshift, const float* __restrict__ gW2,
    const float* __restrict__ gb2, const float* __restrict__ gx,
    const float* __restrict__ gWsc, float* __restrict__ hg) {
  const int bi = blockIdx.x, tid = threadIdx.x;
  if (bi < 4096) {
    int idx = (bi * 256 + tid) * 4;
    int o = idx & 511;
    ushort4 in = *(const ushort4*)&y1u[idx];
    float iv[4] = {bf2f(in.x), bf2f(in.y), bf2f(in.z), bf2f(in.w)};
    unsigned short ov[4];
#pragma unroll
    for (int j = 0; j < 4; j++) {
      float mu = bsum[o + j] * (1.f / NPOS);
      float var = bsq[o + j] * (1.f / NPOS) - mu * mu;
      float sc = lg1[o + j] * rsqrtf(var + EPS);
      float sh = lb1[o + j] - mu * sc;
      ov[j] = f2bf(fmaxf(fmaf(iv[j], sc, sh), 0.f));
    }
    ushort4 out = {ov[0], ov[1], ov[2], ov[3]};
    *(ushort4*)&vv[idx] = out;
  } else {  // gnet2
    int idx = (bi - 4096) * 256 + tid;
    int b = idx & 31, p = idx >> 5;
    float s = gb2[p];
    for (int o = 0; o < MI; o++) {
      float v = fmaxf(fmaf(y1g[o * 32 + b], gscale[o], gshift[o]), 0.f);
      s = fmaf(v, gW2[(size_t)p * MI + o], s);
    }
    for (int c = 0; c < CG; c++) s = fmaf(gx[b * CG + c], gWsc[p * CG + c], s);
    hg[p * 32 + b] = s;
  }
}

// ============ 4: gemm2 (h = v.W2^T + b2 + ys) 128-thr + gln piggyback =======
// grid: 512 GEMM (m = bi&127, n = bi>>7) + 32 gln
__global__ __launch_bounds__(128, 4) void k_gemm2(
    const unsigned short* __restrict__ vv, const unsigned short* __restrict__ W2b,
    const float* __restrict__ b2, const unsigned short* __restrict__ ysb,
    unsigned short* __restrict__ hb16,
    const float* __restrict__ hg, const float* __restrict__ glng,
    const float* __restrict__ glnb, unsigned short* __restrict__ gnormb) {
  __shared__ __align__(16) unsigned short As[64][32];
  __shared__ __align__(16) unsigned short Bs[128][32];
  __shared__ float rb[2];
  const int tid = threadIdx.x, bi = blockIdx.x;
  if (bi >= 512) {  // gln: 128 threads, 4 channels each
    int b = bi - 512;
    float v[4], Lv[4];
    float s = 0.f, s2 = 0.f;
#pragma unroll
    for (int j = 0; j < 4; j++) {
      v[j] = hg[(tid + j * 128) * 32 + b];
      s += v[j]; s2 = fmaf(v[j], v[j], s2);
    }
    s = bs128(s, rb);
    s2 = bs128(s2, rb);
    float mu = s * (1.f / MI);
    float var = s2 * (1.f / MI) - mu * mu;
    float rstd = rsqrtf(var + EPS);
    float n2 = 0.f;
#pragma unroll
    for (int j = 0; j < 4; j++) {
      int p = tid + j * 128;
      Lv[j] = fmaf((v[j] - mu) * rstd, glng[p], glnb[p]);
      n2 = fmaf(Lv[j], Lv[j], n2);
    }
    n2 = bs128(n2, rb);
    float inv = rsqrtf(n2);
#pragma unroll
    for (int j = 0; j < 4; j++)
      gnormb[b * MI + tid + j * 128] = f2bf(Lv[j] * inv);
    return;
  }
  const int w = tid >> 6, lane = tid & 63;
  const int m0 = (bi & 127) * 64, p0 = (bi >> 7) * 128;
  const int sr = lane >> 2, sc = (lane & 3) * 8;
  const int lm = lane & 15, q = lane >> 4;
  f32x4 acc[4][4];
#pragma unroll
  for (int i = 0; i < 4; i++)
#pragma unroll
    for (int j = 0; j < 4; j++) acc[i][j] = f32x4{0.f, 0.f, 0.f, 0.f};

  const unsigned short* pa = vv + (size_t)(m0 + w * 32 + sr) * 512 + sc;
  const unsigned short* pb = W2b + (size_t)(p0 + w * 64 + sr) * 512 + sc;
  for (int k0 = 0; k0 < 512; k0 += 32) {
    __builtin_amdgcn_global_load_lds(
        (const __attribute__((address_space(1))) void*)(pa + k0),
        (__attribute__((address_space(3))) void*)&As[w * 32][0], 16, 0, 0);
    __builtin_amdgcn_global_load_lds(
        (const __attribute__((address_space(1))) void*)(pa + 16 * 512 + k0),
        (__attribute__((address_space(3))) void*)&As[w * 32 + 16][0], 16, 0, 0);
    __builtin_amdgcn_global_load_lds(
        (const __attribute__((address_space(1))) void*)(pb + k0),
        (__attribute__((address_space(3))) void*)&Bs[w * 64][0], 16, 0, 0);
    __builtin_amdgcn_global_load_lds(
        (const __attribute__((address_space(1))) void*)(pb + 16 * 512 + k0),
        (__attribute__((address_space(3))) void*)&Bs[w * 64 + 16][0], 16, 0, 0);
    __builtin_amdgcn_global_load_lds(
        (const __attribute__((address_space(1))) void*)(pb + 32 * 512 + k0),
        (__attribute__((address_space(3))) void*)&Bs[w * 64 + 32][0], 16, 0, 0);
    __builtin_amdgcn_global_load_lds(
        (const __attribute__((address_space(1))) void*)(pb + 48 * 512 + k0),
        (__attribute__((address_space(3))) void*)&Bs[w * 64 + 48][0], 16, 0, 0);
    __syncthreads();
    bf16x8 af[4], bfr[4];
#pragma unroll
    for (int mi = 0; mi < 4; mi++)
      af[mi] = *(const bf16x8*)&As[mi * 16 + lm][q * 8];
#pragma unroll
    for (int ni = 0; ni < 4; ni++)
      bfr[ni] = *(const bf16x8*)&Bs[w * 64 + ni * 16 + lm][q * 8];
#pragma unroll
    for (int mi = 0; mi < 4; mi++)
#pragma unroll
      for (int ni = 0; ni < 4; ni++)
        acc[mi][ni] = __builtin_amdgcn_mfma_f32_16x16x32_bf16(
            af[mi], bfr[ni], acc[mi][ni], 0, 0, 0);
    __syncthreads();
  }
  const int row0 = m0 + q * 4;
#pragma unroll
  for (int ni = 0; ni < 4; ni++) {
    int p = p0 + w * 64 + ni * 16 + lm;
    float bias = b2[p];
#pragma unroll
    for (int mi = 0; mi < 4; mi++)
#pragma unroll
      for (int r = 0; r < 4; r++) {
        size_t off = (size_t)(row0 + mi * 16 + r) * 512 + p;
        hb16[off] = f2bf(acc[mi][ni][r] + bias + bf2f(ysb[off]));
      }
  }
}

// ============ 5: LayerNorm, wave-per-row -> L_hat bf16 (pre-normalized) =====
__global__ __launch_bounds__(256) void k_ln(
    const unsigned short* __restrict__ hb16, const float* __restrict__ lng,
    const float* __restrict__ lnb, unsigned short* __restrict__ Lb) {
  const int tid = threadIdx.x;
  const int r = blockIdx.x * 4 + (tid >> 6), lane = tid & 63;
  const unsigned short* row = hb16 + (size_t)r * 512 + lane * 8;
  ushort4 u0 = *(const ushort4*)row;
  ushort4 u1 = *(const ushort4*)(row + 4);
  float v[8] = {bf2f(u0.x), bf2f(u0.y), bf2f(u0.z), bf2f(u0.w),
                bf2f(u1.x), bf2f(u1.y), bf2f(u1.z), bf2f(u1.w)};
  float s = 0.f, s2 = 0.f;
#pragma unroll
  for (int j = 0; j < 8; j++) { s += v[j]; s2 = fmaf(v[j], v[j], s2); }
  s = wave_sum(s);
  s2 = wave_sum(s2);
  float mu = s * (1.f / MI);
  float var = s2 * (1.f / MI) - mu * mu;
  float rstd = rsqrtf(var + EPS);
  float4 g0 = *(const float4*)&lng[lane * 8];
  float4 g1 = *(const float4*)&lng[lane * 8 + 4];
  float4 bb0 = *(const float4*)&lnb[lane * 8];
  float4 bb1 = *(const float4*)&lnb[lane * 8 + 4];
  float gg[8] = {g0.x, g0.y, g0.z, g0.w, g1.x, g1.y, g1.z, g1.w};
  float bz[8] = {bb0.x, bb0.y, bb0.z, bb0.w, bb1.x, bb1.y, bb1.z, bb1.w};
  float L[8], n2 = 0.f;
#pragma unroll
  for (int j = 0; j < 8; j++) {
    L[j] = fmaf((v[j] - mu) * rstd, gg[j], bz[j]);
    n2 = fmaf(L[j], L[j], n2);
  }
  n2 = wave_sum(n2);
  float inv = rsqrtf(n2);
  unsigned short* orow = Lb + (size_t)r * 512 + lane * 8;
  ushort4 o0 = {f2bf(L[0] * inv), f2bf(L[1] * inv), f2bf(L[2] * inv), f2bf(L[3] * inv)};
  ushort4 o1 = {f2bf(L[4] * inv), f2bf(L[5] * inv), f2bf(L[6] * inv), f2bf(L[7] * inv)};
  *(ushort4*)orow = o0;
  *(ushort4*)(orow + 4) = o1;
}

// ============ 6: U = gnorm (32x512) x Lhat^T (8192x512) via MFMA ============
__global__ __launch_bounds__(256) void k_u(
    const unsigned short* __restrict__ g, const unsigned short* __restrict__ Lb,
    float* __restrict__ U) {
  const int tid = threadIdx.x;
  const int w = tid >> 6, lane = tid & 63;
  const int lm = lane & 15, q = lane >> 4;
  const int rbase = blockIdx.x * 128 + w * 32;
  f32x4 acc[2][2];
#pragma unroll
  for (int i = 0; i < 2; i++)
#pragma unroll
    for (int j = 0; j < 2; j++) acc[i][j] = f32x4{0.f, 0.f, 0.f, 0.f};
  for (int k0 = 0; k0 < 512; k0 += 32) {
    bf16x8 af[2], bfr[2];
#pragma unroll
    for (int mi = 0; mi < 2; mi++)
      af[mi] = *(const bf16x8*)&g[(size_t)(mi * 16 + lm) * 512 + k0 + q * 8];
#pragma unroll
    for (int ni = 0; ni < 2; ni++)
      bfr[ni] = *(const bf16x8*)&Lb[(size_t)(rbase + ni * 16 + lm) * 512 + k0 + q * 8];
#pragma unroll
    for (int mi = 0; mi < 2; mi++)
#pragma unroll
      for (int ni = 0; ni < 2; ni++)
        acc[mi][ni] = __builtin_amdgcn_mfma_f32_16x16x32_bf16(
            af[mi], bfr[ni], acc[mi][ni], 0, 0, 0);
  }
#pragma unroll
  for (int mi = 0; mi < 2; mi++)
#pragma unroll
    for (int ni = 0; ni < 2; ni++) {
      int row = rbase + ni * 16 + lm;
#pragma unroll
      for (int r = 0; r < 4; r++) {
        int gi = mi * 16 + q * 4 + r;
        U[(size_t)gi * NPOS + row] = acc[mi][ni][r];
      }
    }
}

// ============ 7: per-(row,chunk) masked max & sumexp partials ===============
// grid (8, 32): blockIdx.y = n, blockIdx.x = 1024-col chunk
__global__ __launch_bounds__(256) void k_rowstats(
    const float* __restrict__ U, float* __restrict__ pmax, float* __restrict__ psum) {
  __shared__ float rb[4];
  const int n = blockIdx.y, c = blockIdx.x, tid = threadIdx.x;
  float4 v = ((const float4*)(U + (size_t)n * NPOS + c * 1024))[tid];
  int m = (c * 1024 + tid * 4) >> 8;
  if (m == n) { v.x = v.y = v.z = v.w = -1e30f; }
  float mx = fmaxf(fmaxf(v.x, v.y), fmaxf(v.z, v.w));
  mx = block_max(mx, rb);
  float s = expf(v.x - mx) + expf(v.y - mx) + expf(v.z - mx) + expf(v.w - mx);
  s = block_sum(s, rb);
  if (tid == 0) { pmax[n * 8 + c] = mx; psum[n * 8 + c] = s; }
}

// ============ 8: loss = mean(lse - u_p), combining partials =================
__global__ __launch_bounds__(256) void k_loss(
    const float* __restrict__ U, const float* __restrict__ pmax,
    const float* __restrict__ psum, float* __restrict__ out) {
  __shared__ float rb[4];
  __shared__ float cm[32], cs[32];
  const int tid = threadIdx.x;
  if (tid < 32) {
    float M = -1e30f;
#pragma unroll
    for (int c = 0; c < 8; c++) M = fmaxf(M, pmax[tid * 8 + c]);
    float S = 0.f;
#pragma unroll
    for (int c = 0; c < 8; c++) S += psum[tid * 8 + c] * expf(pmax[tid * 8 + c] - M);
    cm[tid] = M; cs[tid] = S;
  }
  __syncthreads();
  float s = 0.f;
  for (int i = tid; i < NPOS; i += 256) {
    int n = i >> 8, t = i & 255;
    float up = U[(size_t)n * NPOS + n * T + t] * (1.f / TEMP);
    float M = cm[n], S = cs[n];
    float mx = fmaxf(up, M);
    float lse = mx + logf(expf(up - mx) + S * expf(M - mx));
    s += lse - up;
  }
  s = block_sum(s, rb);
  if (tid == 0) out[0] = s * (1.f / NPOS);
}

extern "C" void kernel_launch(void* const* d_in, const int* in_sizes, int n_in,
                              void* d_out, int out_size, void* d_ws, size_t ws_size,
                              hipStream_t stream) {
  (void)in_sizes; (void)n_in; (void)out_size; (void)ws_size;
  const float* x    = (const float*)d_in[0];
  const float* gx   = (const float*)d_in[1];
  const float* lW1  = (const float*)d_in[2];
  const float* lg1  = (const float*)d_in[3];
  const float* lb1  = (const float*)d_in[4];
  const float* lW2  = (const float*)d_in[5];
  const float* lb2  = (const float*)d_in[6];
  const float* lWs  = (const float*)d_in[7];
  const float* llng = (const float*)d_in[8];
  const float* llnb = (const float*)d_in[9];
  const float* gW1  = (const float*)d_in[10];
  const float* gg1  = (const float*)d_in[11];
  const float* gb1  = (const float*)d_in[12];
  const float* gW2  = (const float*)d_in[13];
  const float* gb2  = (const float*)d_in[14];
  const float* gWs  = (const float*)d_in[15];
  const float* glng = (const float*)d_in[16];
  const float* glnb = (const float*)d_in[17];

  char* wsb = (char*)d_ws;
  unsigned short* xT     = (unsigned short*)(wsb);             // [8192][1536] bf16
  unsigned short* Wc     = (unsigned short*)(wsb + 25165824);  // [1024][1536] bf16
  unsigned short* W2b    = (unsigned short*)(wsb + 28311552);  // [512][512] bf16
  unsigned short* y1u    = (unsigned short*)(wsb + 28835840);  // [8192][512] bf16
  unsigned short* ysb    = (unsigned short*)(wsb + 37224448);  // [8192][512] bf16
  unsigned short* vv     = (unsigned short*)(wsb + 45613056);  // [8192][512] bf16
  unsigned short* hb16   = (unsigned short*)(wsb + 54001664);  // [8192][512] bf16
  unsigned short* Lb     = (unsigned short*)(wsb + 62390272);  // [8192][512] bf16
  float* U               = (float*)(wsb + 70778880);           // [32][8192] f32
  float* bsum            = (float*)(wsb + 71827456);           // [512]
  float* bsq             = (float*)(wsb + 71829504);           // [512]
  float* y1g             = (float*)(wsb + 71831552);           // [512][32]
  float* gscale          = (float*)(wsb + 71897088);           // [512]
  float* gshift          = (float*)(wsb + 71899136);           // [512]
  float* hg              = (float*)(wsb + 71901184);           // [512][32]
  unsigned short* gnormb = (unsigned short*)(wsb + 71966720);  // [32][512] bf16
  float* pmax            = (float*)(wsb + 71999488);           // [32][8]
  float* psum            = (float*)(wsb + 72000512);           // [32][8]

  k_prep<<<dim3(4929), 256, 0, stream>>>(x, lW1, lWs, lW2, gx, gW1, xT, Wc, W2b,
                                         y1g, bsum);
  k_gemm1<<<dim3(1028), 128, 0, stream>>>(xT, Wc, y1u, ysb, bsum, bsq,
                                          y1g, gg1, gb1, gscale, gshift);
  k_bnapp<<<dim3(4160), 256, 0, stream>>>(y1u, bsum, bsq, lg1, lb1, vv,
                                          y1g, gscale, gshift, gW2, gb2, gx, gWs, hg);
  k_gemm2<<<dim3(544), 128, 0, stream>>>(vv, W2b, lb2, ysb, hb16,
                                         hg, glng, glnb, gnormb);
  k_ln<<<dim3(2048), 256, 0, stream>>>(hb16, llng, llnb, Lb);
  k_u<<<dim3(64), 256, 0, stream>>>(gnormb, Lb, U);
  k_rowstats<<<dim3(8, 32), 256, 0, stream>>>(U, pmax, psum);
  k_loss<<<dim3(1), 256, 0, stream>>>(U, pmax, psum, (float*)d_out);
}